// Round 1
// 84.450 us; speedup vs baseline: 1.0151x; 1.0151x over previous
//
#include <hip/hip_runtime.h>

// LearnableDemosaick: B=16,H=512,W=512,K=8,f=5, fp32.
// out = is_green ? mosaick : softmax_k(sel_conv) . green_conv
// is_green = (y%2)==(x%2). Edge-clamped 5x5 cross-correlation.
//
// Round-11: combined-M MFMA. Even-row and odd-row convs share B fragments;
// previously odd-row filters ran as a SECOND 3-MFMA chain while M-rows 16..31
// of the first sat zeroed (chok=mm<16). Pack odd-row filters into M 16..31:
// one 3-MFMA chain per pp computes BOTH rows (12->6 MFMA/thread, 6->3 A-frags,
// 2 f32x16 accs -> 1). B fragments deduped across pp (Ba(1)=Bb(0), Bb(1)=Bc(0)):
// 24->16 ds_read_b32. A-build folded back in-kernel (hides under staging
// latency per R9~R10 neutrality) -> drops the serial build_frags launch + ws.
// Staging unified: y-clamp via clamped row pointer (free), per-element x-clamp
// only for the 2 edge chunks of bx={0,7} blocks -> no more all-scalar path for
// the 30% boundary blocks.

typedef float f32x16 __attribute__((ext_vector_type(16)));
typedef short s16x8  __attribute__((ext_vector_type(8)));

#define HH 512
#define WW 512
#define TW 64
#define TH 16
#define RS 80     // LDS row stride (bf16 elems) = 160 B
#define NROW 20   // TH + 4

__device__ __forceinline__ unsigned short bf16rne(float x) {
    unsigned u = __float_as_uint(x);
    u += 0x7fffu + ((u >> 16) & 1u);
    return (unsigned short)(u >> 16);
}
__device__ __forceinline__ int pk2(float hi, float lo) {
    return (int)((((unsigned)bf16rne(hi)) << 16) | (unsigned)bf16rne(lo));
}
__device__ __forceinline__ float hi16(int v) { return __uint_as_float(((unsigned)v) & 0xffff0000u); }
__device__ __forceinline__ float lo16(int v) { return __uint_as_float(((unsigned)v) << 16); }

__global__ __launch_bounds__(256) void demosaick_kernel(
    const float* __restrict__ mos,   // [B,1,H,W]
    const float* __restrict__ sf,    // [5,5,8]
    const float* __restrict__ gf,    // [5,5,8]
    float* __restrict__ out)         // [B,1,H,W]
{
    __shared__ alignas(16) unsigned short tileS[NROW * RS];

    const int tid   = threadIdx.x;
    const int tileX = blockIdx.x * TW;    // even
    const int tileY = blockIdx.y * TH;    // even
    const float* img = mos + (size_t)blockIdx.z * HH * WW;

    // ---- stage bf16 tile: rows tileY-2..tileY+17 (y-clamped), cols tileX-2..+69 ----
    if (tid < 180) {                       // 20 rows x 9 chunks of 8 elems
        int r = tid / 9, s = tid - 9 * r;
        int gy = min(max(tileY - 2 + r, 0), HH - 1);
        const float* rowp = img + (size_t)gy * WW;
        int cx = tileX - 2 + 8 * s;
        int4 d;
        if (cx >= 0 && cx + 8 <= WW) {     // all chunks except x-edge ones
            const float2* src = (const float2*)(rowp + cx);
            float2 v0 = src[0], v1 = src[1], v2 = src[2], v3 = src[3];
            d.x = pk2(v0.y, v0.x);
            d.y = pk2(v1.y, v1.x);
            d.z = pk2(v2.y, v2.x);
            d.w = pk2(v3.y, v3.x);
        } else {                           // bx==0 s==0 / bx==7 s==8 only
            float v[8];
#pragma unroll
            for (int j = 0; j < 8; ++j)
                v[j] = rowp[min(max(cx + j, 0), WW - 1)];
            d.x = pk2(v[1], v[0]);
            d.y = pk2(v[3], v[2]);
            d.z = pk2(v[5], v[4]);
            d.w = pk2(v[7], v[6]);
        }
        *(int4*)&tileS[r * RS + 8 * s] = d;
    }

    // ---- per-thread A fragments (3), built in-register; hides under staging ----
    // A layout (32x32x16): lane holds A[m=lane&31][k=8h+j].
    // M rows 0..15: even-output-row filters (c=m>>1, tg=m&1), dx = j-1.
    // M rows 16..31: odd-output-row filters, dx = j. B is shared between rows.
    const int lane = tid & 63;
    const int m    = lane & 31;
    const int h    = lane >> 5;
    const int mc   = m & 15;
    const int c    = mc >> 1;
    const float* fb = (mc & 1) ? gf : sf;

    s16x8 A0 = {0, 0, 0, 0, 0, 0, 0, 0}, A1 = A0, A2 = A0;
#pragma unroll
    for (int j = 0; j < 8; ++j) {
        if (m < 16) {                      // even row: taps dy = -2..2 at rows yE-2..yE+2
            int dx = j - 1;
            if (dx >= 0 && dx < 5) {
                A0[j] = (short)bf16rne(fb[(h * 5 + dx) * 8 + c]);        // yE-2 / yE-1
                A1[j] = (short)bf16rne(fb[((2 + h) * 5 + dx) * 8 + c]);  // yE   / yE+1
                if (h == 0)
                    A2[j] = (short)bf16rne(fb[(20 + dx) * 8 + c]);       // yE+2
            }
        } else {                           // odd row: taps at rows yE-1..yE+3
            if (j < 5) {
                if (h == 1)
                    A0[j] = (short)bf16rne(fb[j * 8 + c]);               // yE-1
                A1[j] = (short)bf16rne(fb[((1 + h) * 5 + j) * 8 + c]);   // yE   / yE+1
                A2[j] = (short)bf16rne(fb[((3 + h) * 5 + j) * 8 + c]);   // yE+2 / yE+3
            }
        }
    }

    __syncthreads();

    const int w = tid >> 6;            // wave -> local rows 4w..4w+3
    const int n = lane & 31;           // pixel column index
    const int* tb = (const int*)tileS; // 40 ints per row
    float* outp = out + (size_t)blockIdx.z * HH * WW;

    // ---- B fragments: unique tile rows 4w+h+{0,2,4,6} (deduped across pp) ----
    union { int4 v; s16x8 s; } F0, F1, F2, F3;
    {
        const int i0 = (4 * w + h) * 40 + n;
        F0.v.x = tb[i0];       F0.v.y = tb[i0 + 1];   F0.v.z = tb[i0 + 2];   F0.v.w = tb[i0 + 3];
        F1.v.x = tb[i0 + 80];  F1.v.y = tb[i0 + 81];  F1.v.z = tb[i0 + 82];  F1.v.w = tb[i0 + 83];
        F2.v.x = tb[i0 + 160]; F2.v.y = tb[i0 + 161]; F2.v.z = tb[i0 + 162]; F2.v.w = tb[i0 + 163];
        F3.v.x = tb[i0 + 240]; F3.v.y = tb[i0 + 241]; F3.v.z = tb[i0 + 242]; F3.v.w = tb[i0 + 243];
    }

#pragma unroll
    for (int pp = 0; pp < 2; ++pp) {
        const s16x8 Ba = (pp == 0) ? F0.s : F1.s;
        const s16x8 Bb = (pp == 0) ? F1.s : F2.s;
        const s16x8 Bc = (pp == 0) ? F2.s : F3.s;

        f32x16 acc = (f32x16)(0.f);
        acc = __builtin_amdgcn_mfma_f32_32x32x16_bf16(A0, Ba, acc, 0, 0, 0);
        acc = __builtin_amdgcn_mfma_f32_32x32x16_bf16(A1, Bb, acc, 0, 0, 0);
        acc = __builtin_amdgcn_mfma_f32_32x32x16_bf16(A2, Bc, acc, 0, 0, 0);

        // regs 0..7  -> M rows {0..3,8..11}+4h   = even-row (filter,type) pairs
        // regs 8..15 -> M rows {16..19,24..27}+4h = odd-row  (filter,type) pairs
        float denE = 0.f, numE = 0.f, denO = 0.f, numO = 0.f;
#pragma unroll
        for (int j = 0; j < 4; ++j) {
            float e  = __expf(acc[2 * j]);
            denE += e;  numE = fmaf(e,  acc[2 * j + 1], numE);
            float eo = __expf(acc[8 + 2 * j]);
            denO += eo; numO = fmaf(eo, acc[9 + 2 * j], numO);
        }
        int ndE  = pk2(numE, denE), ndO = pk2(numO, denO);
        int ndE2 = __shfl_xor(ndE, 32);
        int ndO2 = __shfl_xor(ndO, 32);
        numE += hi16(ndE2); denE += lo16(ndE2);
        numO += hi16(ndO2); denO += lo16(ndO2);
        const float interpE = numE * __builtin_amdgcn_rcpf(denE);
        const float interpO = numO * __builtin_amdgcn_rcpf(denO);

        if (h == 0) {
            const int x0 = tileX + 2 * n;              // even
            const int yE = tileY + 4 * w + 2 * pp;     // even
            // even row: green at x0, interp at x0+1
            float2 stE; stE.x = img[(size_t)yE * WW + x0]; stE.y = interpE;
            *(float2*)(outp + (size_t)yE * WW + x0) = stE;
            // odd row: interp at x0, green at x0+1
            float2 stO; stO.x = interpO; stO.y = img[(size_t)(yE + 1) * WW + x0 + 1];
            *(float2*)(outp + (size_t)(yE + 1) * WW + x0) = stO;
        }
    }
}

extern "C" void kernel_launch(void* const* d_in, const int* in_sizes, int n_in,
                              void* d_out, int out_size, void* d_ws, size_t ws_size,
                              hipStream_t stream) {
    const float* mos = (const float*)d_in[0];
    const float* sf  = (const float*)d_in[1];
    const float* gf  = (const float*)d_in[2];
    float* out = (float*)d_out;

    const int B = in_sizes[0] / (HH * WW * 4) > 0 ? in_sizes[0] / (HH * WW) : 16; // sizes in elems
    dim3 grid(WW / TW, HH / TH, in_sizes[0] / (HH * WW));  // (8, 32, 16)
    dim3 block(256);
    demosaick_kernel<<<grid, block, 0, stream>>>(mos, sf, gf, out);
    (void)B; (void)d_ws; (void)ws_size; (void)n_in; (void)out_size;
}

// Round 2
// 81.668 us; speedup vs baseline: 1.0497x; 1.0341x over previous
//
#include <hip/hip_runtime.h>

// LearnableDemosaick: B=16,H=512,W=512,K=8,f=5, fp32.
// out = is_green ? mosaick : softmax_k(sel_conv) . green_conv
// is_green = (y%2)==(x%2). Edge-clamped 5x5 cross-correlation.
//
// Round-12: wave-specialized A-build. R11 (half the MFMAs, no pre-kernel)
// was ~neutral vs R10 => demosaick is not MFMA-bound; biggest remaining
// per-thread block is the A-fragment build (~150 VALU + 20 scalar filter
// loads, identical across all waves/blocks - only 64 distinct results).
// New structure: wave 3 (idle during staging, which is tid<180) builds the
// 64 per-lane fragment triples and publishes via 3 KB LDS; waves 0-2 stage
// the pixel tile concurrently. After the single barrier everyone reads its
// fragments with 3 ds_read_b128. Kills ~75% of build VALU and removes it
// from the staging critical path. Everything else identical to R11
// (passing, absmax 2e-3).

typedef float f32x16 __attribute__((ext_vector_type(16)));
typedef short s16x8  __attribute__((ext_vector_type(8)));

#define HH 512
#define WW 512
#define TW 64
#define TH 16
#define RS 80     // LDS row stride (bf16 elems) = 160 B
#define NROW 20   // TH + 4

__device__ __forceinline__ unsigned short bf16rne(float x) {
    unsigned u = __float_as_uint(x);
    u += 0x7fffu + ((u >> 16) & 1u);
    return (unsigned short)(u >> 16);
}
__device__ __forceinline__ int pk2(float hi, float lo) {
    return (int)((((unsigned)bf16rne(hi)) << 16) | (unsigned)bf16rne(lo));
}
__device__ __forceinline__ float hi16(int v) { return __uint_as_float(((unsigned)v) & 0xffff0000u); }
__device__ __forceinline__ float lo16(int v) { return __uint_as_float(((unsigned)v) << 16); }

__global__ __launch_bounds__(256) void demosaick_kernel(
    const float* __restrict__ mos,   // [B,1,H,W]
    const float* __restrict__ sf,    // [5,5,8]
    const float* __restrict__ gf,    // [5,5,8]
    float* __restrict__ out)         // [B,1,H,W]
{
    __shared__ alignas(16) unsigned short tileS[NROW * RS];   // 3200 B
    __shared__ alignas(16) short fragS[64 * 24];              // 3072 B

    const int tid   = threadIdx.x;
    const int tileX = blockIdx.x * TW;    // even
    const int tileY = blockIdx.y * TH;    // even
    const float* img = mos + (size_t)blockIdx.z * HH * WW;

    const int lane = tid & 63;
    const int h    = lane >> 5;

    s16x8 A0 = {0, 0, 0, 0, 0, 0, 0, 0}, A1 = A0, A2 = A0;

    if (tid < 180) {
        // ---- waves 0-2: stage bf16 tile rows tileY-2..tileY+17 (y-clamped),
        //      cols tileX-2..+69; 20 rows x 9 chunks of 8 elems ----
        int r = tid / 9, s = tid - 9 * r;
        int gy = min(max(tileY - 2 + r, 0), HH - 1);
        const float* rowp = img + (size_t)gy * WW;
        int cx = tileX - 2 + 8 * s;
        int4 d;
        if (cx >= 0 && cx + 8 <= WW) {     // all chunks except x-edge ones
            const float2* src = (const float2*)(rowp + cx);
            float2 v0 = src[0], v1 = src[1], v2 = src[2], v3 = src[3];
            d.x = pk2(v0.y, v0.x);
            d.y = pk2(v1.y, v1.x);
            d.z = pk2(v2.y, v2.x);
            d.w = pk2(v3.y, v3.x);
        } else {                           // bx==0 s==0 / bx==7 s==8 only
            float v[8];
#pragma unroll
            for (int j = 0; j < 8; ++j)
                v[j] = rowp[min(max(cx + j, 0), WW - 1)];
            d.x = pk2(v[1], v[0]);
            d.y = pk2(v[3], v[2]);
            d.z = pk2(v[5], v[4]);
            d.w = pk2(v[7], v[6]);
        }
        *(int4*)&tileS[r * RS + 8 * s] = d;
    } else if (tid >= 192) {
        // ---- wave 3: build the 64 per-lane A-fragment triples ----
        // A layout (32x32x16): lane holds A[m=lane&31][k=8h+j].
        // M rows 0..15: even-output-row filters (c, type), dx = j-1.
        // M rows 16..31: odd-output-row filters, dx = j. B shared between rows.
        const int m  = lane & 31;
        const int mc = m & 15;
        const int c  = mc >> 1;
        const float* fb = (mc & 1) ? gf : sf;
#pragma unroll
        for (int j = 0; j < 8; ++j) {
            if (m < 16) {                  // even row: taps at rows yE-2..yE+2
                int dx = j - 1;
                if (dx >= 0 && dx < 5) {
                    A0[j] = (short)bf16rne(fb[(h * 5 + dx) * 8 + c]);        // yE-2 / yE-1
                    A1[j] = (short)bf16rne(fb[((2 + h) * 5 + dx) * 8 + c]);  // yE   / yE+1
                    if (h == 0)
                        A2[j] = (short)bf16rne(fb[(20 + dx) * 8 + c]);       // yE+2
                }
            } else {                       // odd row: taps at rows yE-1..yE+3
                if (j < 5) {
                    if (h == 1)
                        A0[j] = (short)bf16rne(fb[j * 8 + c]);               // yE-1
                    A1[j] = (short)bf16rne(fb[((1 + h) * 5 + j) * 8 + c]);   // yE   / yE+1
                    A2[j] = (short)bf16rne(fb[((3 + h) * 5 + j) * 8 + c]);   // yE+2 / yE+3
                }
            }
        }
        s16x8* dst = (s16x8*)&fragS[lane * 24];
        dst[0] = A0; dst[1] = A1; dst[2] = A2;
    }

    __syncthreads();

    if (tid < 192) {                       // waves 0-2 fetch their fragments
        const s16x8* sfr = (const s16x8*)&fragS[lane * 24];
        A0 = sfr[0]; A1 = sfr[1]; A2 = sfr[2];
    }

    const int w = tid >> 6;            // wave -> local rows 4w..4w+3
    const int n = lane & 31;           // pixel column index
    const int* tb = (const int*)tileS; // 40 ints per row
    float* outp = out + (size_t)blockIdx.z * HH * WW;

    // ---- B fragments: unique tile rows 4w+h+{0,2,4,6} (deduped across pp) ----
    union { int4 v; s16x8 s; } F0, F1, F2, F3;
    {
        const int i0 = (4 * w + h) * 40 + n;
        F0.v.x = tb[i0];       F0.v.y = tb[i0 + 1];   F0.v.z = tb[i0 + 2];   F0.v.w = tb[i0 + 3];
        F1.v.x = tb[i0 + 80];  F1.v.y = tb[i0 + 81];  F1.v.z = tb[i0 + 82];  F1.v.w = tb[i0 + 83];
        F2.v.x = tb[i0 + 160]; F2.v.y = tb[i0 + 161]; F2.v.z = tb[i0 + 162]; F2.v.w = tb[i0 + 163];
        F3.v.x = tb[i0 + 240]; F3.v.y = tb[i0 + 241]; F3.v.z = tb[i0 + 242]; F3.v.w = tb[i0 + 243];
    }

#pragma unroll
    for (int pp = 0; pp < 2; ++pp) {
        const s16x8 Ba = (pp == 0) ? F0.s : F1.s;
        const s16x8 Bb = (pp == 0) ? F1.s : F2.s;
        const s16x8 Bc = (pp == 0) ? F2.s : F3.s;

        f32x16 acc = (f32x16)(0.f);
        acc = __builtin_amdgcn_mfma_f32_32x32x16_bf16(A0, Ba, acc, 0, 0, 0);
        acc = __builtin_amdgcn_mfma_f32_32x32x16_bf16(A1, Bb, acc, 0, 0, 0);
        acc = __builtin_amdgcn_mfma_f32_32x32x16_bf16(A2, Bc, acc, 0, 0, 0);

        // regs 0..7  -> M rows {0..3,8..11}+4h   = even-row (filter,type) pairs
        // regs 8..15 -> M rows {16..19,24..27}+4h = odd-row (filter,type) pairs
        float denE = 0.f, numE = 0.f, denO = 0.f, numO = 0.f;
#pragma unroll
        for (int j = 0; j < 4; ++j) {
            float e  = __expf(acc[2 * j]);
            denE += e;  numE = fmaf(e,  acc[2 * j + 1], numE);
            float eo = __expf(acc[8 + 2 * j]);
            denO += eo; numO = fmaf(eo, acc[9 + 2 * j], numO);
        }
        int ndE  = pk2(numE, denE), ndO = pk2(numO, denO);
        int ndE2 = __shfl_xor(ndE, 32);
        int ndO2 = __shfl_xor(ndO, 32);
        numE += hi16(ndE2); denE += lo16(ndE2);
        numO += hi16(ndO2); denO += lo16(ndO2);
        const float interpE = numE * __builtin_amdgcn_rcpf(denE);
        const float interpO = numO * __builtin_amdgcn_rcpf(denO);

        if (h == 0) {
            const int x0 = tileX + 2 * n;              // even
            const int yE = tileY + 4 * w + 2 * pp;     // even
            // even row: green at x0, interp at x0+1
            float2 stE; stE.x = img[(size_t)yE * WW + x0]; stE.y = interpE;
            *(float2*)(outp + (size_t)yE * WW + x0) = stE;
            // odd row: interp at x0, green at x0+1
            float2 stO; stO.x = interpO; stO.y = img[(size_t)(yE + 1) * WW + x0 + 1];
            *(float2*)(outp + (size_t)(yE + 1) * WW + x0) = stO;
        }
    }
}

extern "C" void kernel_launch(void* const* d_in, const int* in_sizes, int n_in,
                              void* d_out, int out_size, void* d_ws, size_t ws_size,
                              hipStream_t stream) {
    const float* mos = (const float*)d_in[0];
    const float* sf  = (const float*)d_in[1];
    const float* gf  = (const float*)d_in[2];
    float* out = (float*)d_out;

    const int B = in_sizes[0] / (HH * WW);     // 16
    dim3 grid(WW / TW, HH / TH, B);            // (8, 32, 16) = 4096 blocks
    dim3 block(256);
    demosaick_kernel<<<grid, block, 0, stream>>>(mos, sf, gf, out);
    (void)d_ws; (void)ws_size; (void)n_in; (void)out_size;
}